// Round 3
// baseline (79.742 us; speedup 1.0000x reference)
//
#include <hip/hip_runtime.h>
#include <hip/hip_bf16.h>

// out[s,o] = sum_k x[s,k]*W[o,k]  (bf16 MFMA, split-K=2 partials)
//          + zc_w*8*sum_r A[o,r]*t[r,s] + zc_b*xsum[s] + bias[o]   (fp32 exact)
// t[r,s] = sum_k B[r,k]*x[s,k],  xsum[s] = sum_k x[s,k]

typedef __attribute__((ext_vector_type(8))) short bf16x8;
typedef __attribute__((ext_vector_type(4))) float f32x4;

#define MDIM 512
#define NDIM 4096
#define KDIM 4096
#define BM 64
#define BN 64
#define BK 64
#define NT (KDIM / BK)   // 64 K-tiles total

static __device__ inline unsigned short f2bf(float f) {
  return __bfloat16_as_ushort(__float2bfloat16(f));  // v_cvt_pk_bf16_f32
}

static __device__ inline bf16x8 pack8(f32x4 a, f32x4 b) {
  bf16x8 v;
  v[0] = (short)f2bf(a[0]); v[1] = (short)f2bf(a[1]);
  v[2] = (short)f2bf(a[2]); v[3] = (short)f2bf(a[3]);
  v[4] = (short)f2bf(b[0]); v[5] = (short)f2bf(b[1]);
  v[6] = (short)f2bf(b[2]); v[7] = (short)f2bf(b[3]);
  return v;
}

struct Stage { f32x4 x0, x1, x2, x3, w0, w1, w2, w3; };

// ---------------- t / xsum kernel ----------------
__global__ __launch_bounds__(256) void tk_kernel(
    const float* __restrict__ x, const float* __restrict__ B,
    float* __restrict__ t, float* __restrict__ xs) {
  int s = blockIdx.x;
  int tid = threadIdx.x;
  const float* xr = x + (long)s * KDIM;
  float a0 = 0.f, a1 = 0.f, a2 = 0.f, a3 = 0.f, a4 = 0.f;
  for (int k = tid * 4; k < KDIM; k += 1024) {
    f32x4 xv = *(const f32x4*)&xr[k];
    f32x4 b0 = *(const f32x4*)&B[0 * KDIM + k];
    f32x4 b1 = *(const f32x4*)&B[1 * KDIM + k];
    f32x4 b2 = *(const f32x4*)&B[2 * KDIM + k];
    f32x4 b3 = *(const f32x4*)&B[3 * KDIM + k];
    a0 += xv[0]*b0[0] + xv[1]*b0[1] + xv[2]*b0[2] + xv[3]*b0[3];
    a1 += xv[0]*b1[0] + xv[1]*b1[1] + xv[2]*b1[2] + xv[3]*b1[3];
    a2 += xv[0]*b2[0] + xv[1]*b2[1] + xv[2]*b2[2] + xv[3]*b2[3];
    a3 += xv[0]*b3[0] + xv[1]*b3[1] + xv[2]*b3[2] + xv[3]*b3[3];
    a4 += xv[0] + xv[1] + xv[2] + xv[3];
  }
  #pragma unroll
  for (int off = 32; off; off >>= 1) {
    a0 += __shfl_down(a0, off, 64);
    a1 += __shfl_down(a1, off, 64);
    a2 += __shfl_down(a2, off, 64);
    a3 += __shfl_down(a3, off, 64);
    a4 += __shfl_down(a4, off, 64);
  }
  __shared__ float red[4][5];
  int w = tid >> 6, l = tid & 63;
  if (l == 0) { red[w][0]=a0; red[w][1]=a1; red[w][2]=a2; red[w][3]=a3; red[w][4]=a4; }
  __syncthreads();
  if (tid == 0) {
    t[0 * MDIM + s] = red[0][0] + red[1][0] + red[2][0] + red[3][0];
    t[1 * MDIM + s] = red[0][1] + red[1][1] + red[2][1] + red[3][1];
    t[2 * MDIM + s] = red[0][2] + red[1][2] + red[2][2] + red[3][2];
    t[3 * MDIM + s] = red[0][3] + red[1][3] + red[2][3] + red[3][3];
    xs[s]           = red[0][4] + red[1][4] + red[2][4] + red[3][4];
  }
}

// ---------------- main GEMM ----------------
// 64x64 tile, BK=64, 256 threads (4 waves 2x2, wave tile 32x32).
// NSPLIT-way split-K: grid (512, NSPLIT). FUSED=true writes out+corr directly,
// else writes fp32 partials to pbuf[ks][M][N].
template<int NSPLIT, bool FUSED>
__global__ __launch_bounds__(256, 4) void gemm_kernel(
    const float* __restrict__ x, const float* __restrict__ W,
    const float* __restrict__ A, const float* __restrict__ bias,
    const float* __restrict__ zcw, const float* __restrict__ zcb,
    const float* __restrict__ t, const float* __restrict__ xs,
    float* __restrict__ dst) {
  __shared__ __align__(16) unsigned short As[2][BM * BK];
  __shared__ __align__(16) unsigned short Ws[2][BN * BK];

  const int bid = blockIdx.x;
  const int ks  = blockIdx.y;
  const int bn = bid % (NDIM / BN);   // 64
  const int bm = bid / (NDIM / BN);   // 8
  const int tid = threadIdx.x;
  const int lane = tid & 63;
  const int wid = tid >> 6;           // 0..3
  const int wm = wid >> 1;            // 0..1
  const int wn = wid & 1;             // 0..1

  const int NTloc = NT / NSPLIT;
  const int kbase = ks * NTloc * BK;  // element offset into K

  // staging map: thread -> (row, 16-float chunk)
  const int srow = tid >> 2;          // 0..63
  const int sc0 = (tid & 3) * 16;     // 0,16,32,48
  const float* xg = x + (long)(bm * BM + srow) * KDIM + kbase + sc0;
  const float* wg = W + (long)(bn * BN + srow) * KDIM + kbase + sc0;
  const int off0 = (srow * BK + sc0) ^ ((srow & 7) << 3);
  const int off1 = (srow * BK + sc0 + 8) ^ ((srow & 7) << 3);

  // fragment read map
  const int fr = lane & 15;
  const int fk = (lane >> 4) * 8;

  f32x4 acc[2][2] = {};
  Stage S0, S1;

  auto load_stage = [&](Stage& S, int kt) {
    const int off = kt * BK;
    S.x0 = *(const f32x4*)(xg + off);      S.x1 = *(const f32x4*)(xg + off + 4);
    S.x2 = *(const f32x4*)(xg + off + 8);  S.x3 = *(const f32x4*)(xg + off + 12);
    S.w0 = *(const f32x4*)(wg + off);      S.w1 = *(const f32x4*)(wg + off + 4);
    S.w2 = *(const f32x4*)(wg + off + 8);  S.w3 = *(const f32x4*)(wg + off + 12);
  };
  auto store_stage = [&](const Stage& S, int buf) {
    *(bf16x8*)&As[buf][off0] = pack8(S.x0, S.x1);
    *(bf16x8*)&As[buf][off1] = pack8(S.x2, S.x3);
    *(bf16x8*)&Ws[buf][off0] = pack8(S.w0, S.w1);
    *(bf16x8*)&Ws[buf][off1] = pack8(S.w2, S.w3);
  };
  auto compute = [&](int buf) {
    #pragma unroll
    for (int kseg = 0; kseg < 2; ++kseg) {
      const int kk = kseg * 32 + fk;
      const int ra0 = wm * 32 + fr;
      const int ra1 = wm * 32 + 16 + fr;
      const int rb0 = wn * 32 + fr;
      const int rb1 = wn * 32 + 16 + fr;
      bf16x8 a0 = *(const bf16x8*)&As[buf][(ra0 * BK + kk) ^ ((ra0 & 7) << 3)];
      bf16x8 a1 = *(const bf16x8*)&As[buf][(ra1 * BK + kk) ^ ((ra1 & 7) << 3)];
      bf16x8 b0 = *(const bf16x8*)&Ws[buf][(rb0 * BK + kk) ^ ((rb0 & 7) << 3)];
      bf16x8 b1 = *(const bf16x8*)&Ws[buf][(rb1 * BK + kk) ^ ((rb1 & 7) << 3)];
      acc[0][0] = __builtin_amdgcn_mfma_f32_16x16x32_bf16(a0, b0, acc[0][0], 0, 0, 0);
      acc[0][1] = __builtin_amdgcn_mfma_f32_16x16x32_bf16(a0, b1, acc[0][1], 0, 0, 0);
      acc[1][0] = __builtin_amdgcn_mfma_f32_16x16x32_bf16(a1, b0, acc[1][0], 0, 0, 0);
      acc[1][1] = __builtin_amdgcn_mfma_f32_16x16x32_bf16(a1, b1, acc[1][1], 0, 0, 0);
    }
  };

  // prologue: tiles 0,1 in flight; stage tile 0
  load_stage(S0, 0);
  load_stage(S1, 1);
  store_stage(S0, 0);
  __syncthreads();

  // body: at iter i -- issue loads i+2, ds_write tile i+1, MFMA tile i, barrier
  auto body = [&](int i, Stage& Sc /*tile i, reuse for i+2*/, Stage& Sn /*tile i+1*/) {
    if (i + 2 < NTloc) load_stage(Sc, i + 2);
    if (i + 1 < NTloc) store_stage(Sn, (i + 1) & 1);
    compute(i & 1);
    __syncthreads();
  };
  for (int ii = 0; ii < NTloc; ii += 2) {
    body(ii, S0, S1);
    body(ii + 1, S1, S0);
  }

  const int s0 = bm * BM + wm * 32;
  const int o0 = bn * BN + wn * 32;
  if (FUSED) {
    const float zw8 = zcw[0] * 8.0f;
    const float zb = zcb[0];
    #pragma unroll
    for (int mi = 0; mi < 2; ++mi) {
      const int sb = s0 + mi * 16 + ((lane >> 4) * 4);
      f32x4 t0 = *(const f32x4*)&t[0 * MDIM + sb];
      f32x4 t1 = *(const f32x4*)&t[1 * MDIM + sb];
      f32x4 t2 = *(const f32x4*)&t[2 * MDIM + sb];
      f32x4 t3 = *(const f32x4*)&t[3 * MDIM + sb];
      f32x4 x4 = *(const f32x4*)&xs[sb];
      #pragma unroll
      for (int ni = 0; ni < 2; ++ni) {
        const int o = o0 + ni * 16 + fr;
        f32x4 a4 = *(const f32x4*)&A[o * 4];
        const float bo = bias[o];
        #pragma unroll
        for (int j = 0; j < 4; ++j) {
          float corr = zw8 * (a4[0] * t0[j] + a4[1] * t1[j] + a4[2] * t2[j] + a4[3] * t3[j])
                     + zb * x4[j] + bo;
          dst[(long)(sb + j) * NDIM + o] = acc[mi][ni][j] + corr;
        }
      }
    }
  } else {
    float* p = dst + (size_t)ks * MDIM * NDIM;
    #pragma unroll
    for (int mi = 0; mi < 2; ++mi) {
      const int sb = s0 + mi * 16 + ((lane >> 4) * 4);
      #pragma unroll
      for (int ni = 0; ni < 2; ++ni) {
        const int o = o0 + ni * 16 + fr;
        #pragma unroll
        for (int j = 0; j < 4; ++j) {
          p[(long)(sb + j) * NDIM + o] = acc[mi][ni][j];
        }
      }
    }
  }
}

// ---------------- split-K reduce + epilogue ----------------
__global__ __launch_bounds__(256) void reduce_kernel(
    const float* __restrict__ p,
    const float* __restrict__ A, const float* __restrict__ bias,
    const float* __restrict__ zcw, const float* __restrict__ zcb,
    const float* __restrict__ t, const float* __restrict__ xs,
    float* __restrict__ out) {
  const long base = ((long)blockIdx.x * 256 + threadIdx.x) * 4;
  const int s = (int)(base / NDIM);
  const int o = (int)(base % NDIM);
  f32x4 v0 = *(const f32x4*)&p[base];
  f32x4 v1 = *(const f32x4*)&p[(long)MDIM * NDIM + base];
  const float zw8 = zcw[0] * 8.0f;
  const float zb = zcb[0];
  const float t0 = t[0 * MDIM + s], t1 = t[1 * MDIM + s];
  const float t2 = t[2 * MDIM + s], t3 = t[3 * MDIM + s];
  const float xv = xs[s];
  f32x4 bo = *(const f32x4*)&bias[o];
  f32x4 r;
  #pragma unroll
  for (int j = 0; j < 4; ++j) {
    f32x4 a4 = *(const f32x4*)&A[(o + j) * 4];
    r[j] = v0[j] + v1[j]
         + zw8 * (a4[0] * t0 + a4[1] * t1 + a4[2] * t2 + a4[3] * t3)
         + zb * xv + bo[j];
  }
  *(f32x4*)&out[base] = r;
}

extern "C" void kernel_launch(void* const* d_in, const int* in_sizes, int n_in,
                              void* d_out, int out_size, void* d_ws, size_t ws_size,
                              hipStream_t stream) {
  const float* x    = (const float*)d_in[0];
  const float* W    = (const float*)d_in[1];
  const float* A    = (const float*)d_in[2];
  const float* B    = (const float*)d_in[3];
  const float* zcw  = (const float*)d_in[4];
  const float* zcb  = (const float*)d_in[5];
  const float* bias = (const float*)d_in[6];
  float* out = (float*)d_out;

  float* t    = (float*)d_ws;               // [4][512]
  float* xs   = t + 4 * MDIM;               // [512]
  float* pbuf = xs + MDIM;                  // [2][512][4096] fp32 partials

  const size_t need = (size_t)(4 * MDIM + MDIM) * 4 + (size_t)2 * MDIM * NDIM * 4;

  tk_kernel<<<MDIM, 256, 0, stream>>>(x, B, t, xs);

  if (ws_size >= need) {
    gemm_kernel<2, false><<<dim3((MDIM / BM) * (NDIM / BN), 2), 256, 0, stream>>>(
        x, W, A, bias, zcw, zcb, t, xs, pbuf);
    reduce_kernel<<<(MDIM * NDIM) / (4 * 256), 256, 0, stream>>>(
        pbuf, A, bias, zcw, zcb, t, xs, out);
  } else {
    gemm_kernel<1, true><<<dim3((MDIM / BM) * (NDIM / BN), 1), 256, 0, stream>>>(
        x, W, A, bias, zcw, zcb, t, xs, out);
  }
}

// Round 4
// 62.997 us; speedup vs baseline: 1.2658x; 1.2658x over previous
//
#include <hip/hip_runtime.h>
#include <hip/hip_bf16.h>

// out[s,o] = sum_k x[s,k]*W[o,k]  (bf16 MFMA, global_load_lds pipeline)
//          + zc_w*8*sum_r A[o,r]*t[r,s] + zc_b*xsum[s] + bias[o]   (fp32 exact)
// prep: W->bf16 (ws), x->bf16 (ws), t[r,s]=sum_k B[r,k]x[s,k], xsum[s]=sum_k x[s,k]

typedef __attribute__((ext_vector_type(8))) short bf16x8;
typedef __attribute__((ext_vector_type(4))) short bf16x4;
typedef __attribute__((ext_vector_type(4))) float f32x4;

#define MDIM 512
#define NDIM 4096
#define KDIM 4096
#define BM 64
#define BN 64
#define BK 64
#define NT (KDIM / BK)   // 64

#define VMCNT(n) asm volatile("s_waitcnt vmcnt(" #n ")" ::: "memory")

static __device__ inline unsigned short f2bf(float f) {
  return __bfloat16_as_ushort(__float2bfloat16(f));  // v_cvt_pk_bf16_f32
}

static __device__ inline bf16x8 pack8(f32x4 a, f32x4 b) {
  bf16x8 v;
  v[0] = (short)f2bf(a[0]); v[1] = (short)f2bf(a[1]);
  v[2] = (short)f2bf(a[2]); v[3] = (short)f2bf(a[3]);
  v[4] = (short)f2bf(b[0]); v[5] = (short)f2bf(b[1]);
  v[6] = (short)f2bf(b[2]); v[7] = (short)f2bf(b[3]);
  return v;
}

static __device__ inline void gll16(const void* g, void* l) {
  __builtin_amdgcn_global_load_lds(
      (const __attribute__((address_space(1))) void*)g,
      (__attribute__((address_space(3))) void*)l, 16, 0, 0);
}

// ---------------- prep: t/xs + x->bf16 (blocks 0..511), W->bf16 (blocks 512+) ----
__global__ __launch_bounds__(256) void prep_kernel(
    const float* __restrict__ x, const float* __restrict__ W,
    const float* __restrict__ B,
    float* __restrict__ t, float* __restrict__ xs,
    unsigned short* __restrict__ xbf, unsigned short* __restrict__ wbf) {
  const int tid = threadIdx.x;
  if (blockIdx.x < MDIM) {
    const int s = blockIdx.x;
    const float* xr = x + (long)s * KDIM;
    float a0 = 0.f, a1 = 0.f, a2 = 0.f, a3 = 0.f, a4 = 0.f;
    for (int k = tid * 4; k < KDIM; k += 1024) {
      f32x4 xv = *(const f32x4*)&xr[k];
      if (xbf) {
        bf16x4 bv;
        bv[0] = (short)f2bf(xv[0]); bv[1] = (short)f2bf(xv[1]);
        bv[2] = (short)f2bf(xv[2]); bv[3] = (short)f2bf(xv[3]);
        *(bf16x4*)&xbf[(long)s * KDIM + k] = bv;
      }
      f32x4 b0 = *(const f32x4*)&B[0 * KDIM + k];
      f32x4 b1 = *(const f32x4*)&B[1 * KDIM + k];
      f32x4 b2 = *(const f32x4*)&B[2 * KDIM + k];
      f32x4 b3 = *(const f32x4*)&B[3 * KDIM + k];
      a0 += xv[0]*b0[0] + xv[1]*b0[1] + xv[2]*b0[2] + xv[3]*b0[3];
      a1 += xv[0]*b1[0] + xv[1]*b1[1] + xv[2]*b1[2] + xv[3]*b1[3];
      a2 += xv[0]*b2[0] + xv[1]*b2[1] + xv[2]*b2[2] + xv[3]*b2[3];
      a3 += xv[0]*b3[0] + xv[1]*b3[1] + xv[2]*b3[2] + xv[3]*b3[3];
      a4 += xv[0] + xv[1] + xv[2] + xv[3];
    }
    #pragma unroll
    for (int off = 32; off; off >>= 1) {
      a0 += __shfl_down(a0, off, 64);
      a1 += __shfl_down(a1, off, 64);
      a2 += __shfl_down(a2, off, 64);
      a3 += __shfl_down(a3, off, 64);
      a4 += __shfl_down(a4, off, 64);
    }
    __shared__ float red[4][5];
    int w = tid >> 6, l = tid & 63;
    if (l == 0) { red[w][0]=a0; red[w][1]=a1; red[w][2]=a2; red[w][3]=a3; red[w][4]=a4; }
    __syncthreads();
    if (tid == 0) {
      t[0 * MDIM + s] = red[0][0] + red[1][0] + red[2][0] + red[3][0];
      t[1 * MDIM + s] = red[0][1] + red[1][1] + red[2][1] + red[3][1];
      t[2 * MDIM + s] = red[0][2] + red[1][2] + red[2][2] + red[3][2];
      t[3 * MDIM + s] = red[0][3] + red[1][3] + red[2][3] + red[3][3];
      xs[s]           = red[0][4] + red[1][4] + red[2][4] + red[3][4];
    }
  } else {
    const long NW = (long)NDIM * KDIM;
    const long stride = (long)(gridDim.x - MDIM) * 256 * 16;
    for (long i = ((long)(blockIdx.x - MDIM) * 256 + tid) * 16; i < NW; i += stride) {
      f32x4 a = *(const f32x4*)&W[i];
      f32x4 b = *(const f32x4*)&W[i + 4];
      f32x4 c = *(const f32x4*)&W[i + 8];
      f32x4 d = *(const f32x4*)&W[i + 12];
      *(bf16x8*)&wbf[i]     = pack8(a, b);
      *(bf16x8*)&wbf[i + 8] = pack8(c, d);
    }
  }
}

// ---------------- main GEMM: global_load_lds, 4-deep ring, counted vmcnt -------
// LDS layout swizzle (both sides, involution): LDS 16B-chunk c of row r holds
// global chunk c ^ (r&7). DMA source address carries the XOR; frag reads re-apply.
__global__ __launch_bounds__(256, 2) void gemm_lds(
    const unsigned short* __restrict__ xb, const unsigned short* __restrict__ wb,
    const float* __restrict__ A, const float* __restrict__ bias,
    const float* __restrict__ zcw, const float* __restrict__ zcb,
    const float* __restrict__ t, const float* __restrict__ xs,
    float* __restrict__ out) {
  __shared__ __align__(16) unsigned short As[4][BM * BK];
  __shared__ __align__(16) unsigned short Ws[4][BN * BK];

  const int bid = blockIdx.x;
  const int bn = bid & 63;
  const int bm = bid >> 6;
  const int tid = threadIdx.x;
  const int lane = tid & 63;
  const int wv = tid >> 6;            // 0..3
  const int wm = wv >> 1;             // 0..1
  const int wn = wv & 1;              // 0..1

  // DMA staging map: wave wv stages rows wv*16..wv*16+15 of both tiles.
  // lane l covers row (l>>3) rel within 8-row group, 16B chunk (l&7), source
  // chunk pre-swizzled: (l&7) ^ (row&7) = (l&7) ^ (l>>3).
  const int srow8 = lane >> 3;
  const int schunk = lane & 7;
  const unsigned short* xrow = xb + (long)(bm * BM + wv * 16 + srow8) * KDIM
                                  + ((schunk ^ srow8) << 3);
  const unsigned short* wrow = wb + (long)(bn * BN + wv * 16 + srow8) * KDIM
                                  + ((schunk ^ srow8) << 3);

  auto STAGE = [&](int kt, int buf) {
    const unsigned short* gx = xrow + kt * BK;
    const unsigned short* gw = wrow + kt * BK;
    gll16(gx,            &As[buf][wv * 1024]);
    gll16(gx + 8 * KDIM, &As[buf][wv * 1024 + 512]);
    gll16(gw,            &Ws[buf][wv * 1024]);
    gll16(gw + 8 * KDIM, &Ws[buf][wv * 1024 + 512]);
  };

  // fragment read map (16x16x32): A row = wm*32 + (lane&15) [+16], k-chunk =
  // kseg*4 + (lane>>4); LDS chunk = gchunk ^ (row&7)
  const int fr = lane & 15;
  const int q = lane >> 4;
  const int frs = fr & 7;
  const int ra0 = wm * 32 + fr, ra1 = ra0 + 16;
  const int rb0 = wn * 32 + fr, rb1 = rb0 + 16;

  f32x4 acc[2][2] = {};

  auto COMPUTE = [&](int buf) {
    #pragma unroll
    for (int kseg = 0; kseg < 2; ++kseg) {
      const int c = (((kseg * 4 + q) ^ frs) << 3);
      bf16x8 a0 = *(const bf16x8*)&As[buf][ra0 * BK + c];
      bf16x8 a1 = *(const bf16x8*)&As[buf][ra1 * BK + c];
      bf16x8 b0 = *(const bf16x8*)&Ws[buf][rb0 * BK + c];
      bf16x8 b1 = *(const bf16x8*)&Ws[buf][rb1 * BK + c];
      acc[0][0] = __builtin_amdgcn_mfma_f32_16x16x32_bf16(a0, b0, acc[0][0], 0, 0, 0);
      acc[0][1] = __builtin_amdgcn_mfma_f32_16x16x32_bf16(a0, b1, acc[0][1], 0, 0, 0);
      acc[1][0] = __builtin_amdgcn_mfma_f32_16x16x32_bf16(a1, b0, acc[1][0], 0, 0, 0);
      acc[1][1] = __builtin_amdgcn_mfma_f32_16x16x32_bf16(a1, b1, acc[1][1], 0, 0, 0);
    }
  };

  // prologue: 3 tiles in flight (12 vmem instrs/wave)
  STAGE(0, 0); STAGE(1, 1); STAGE(2, 2);

  // main loop: wait own tile-kt group (vmcnt 8 leaves 2 groups in flight),
  // raw barrier (no vmcnt(0) drain!), then issue kt+3, compute kt.
  for (int kt = 0; kt < NT - 3; ++kt) {
    VMCNT(8);
    __builtin_amdgcn_s_barrier();
    __builtin_amdgcn_sched_barrier(0);
    STAGE(kt + 3, (kt + 3) & 3);
    COMPUTE(kt & 3);
  }
  VMCNT(8); __builtin_amdgcn_s_barrier(); __builtin_amdgcn_sched_barrier(0);
  COMPUTE((NT - 3) & 3);
  VMCNT(4); __builtin_amdgcn_s_barrier(); __builtin_amdgcn_sched_barrier(0);
  COMPUTE((NT - 2) & 3);
  VMCNT(0); __builtin_amdgcn_s_barrier(); __builtin_amdgcn_sched_barrier(0);
  COMPUTE((NT - 1) & 3);

  // epilogue: exact fp32 low-rank correction + bias
  const float zw8 = zcw[0] * 8.0f;
  const float zb = zcb[0];
  const int s0 = bm * BM + wm * 32;
  const int o0 = bn * BN + wn * 32;
  #pragma unroll
  for (int mi = 0; mi < 2; ++mi) {
    const int sb = s0 + mi * 16 + q * 4;
    f32x4 t0 = *(const f32x4*)&t[0 * MDIM + sb];
    f32x4 t1 = *(const f32x4*)&t[1 * MDIM + sb];
    f32x4 t2 = *(const f32x4*)&t[2 * MDIM + sb];
    f32x4 t3 = *(const f32x4*)&t[3 * MDIM + sb];
    f32x4 x4 = *(const f32x4*)&xs[sb];
    #pragma unroll
    for (int ni = 0; ni < 2; ++ni) {
      const int o = o0 + ni * 16 + fr;
      f32x4 a4 = *(const f32x4*)&A[o * 4];
      const float bo = bias[o];
      #pragma unroll
      for (int j = 0; j < 4; ++j) {
        float corr = zw8 * (a4[0] * t0[j] + a4[1] * t1[j] + a4[2] * t2[j] + a4[3] * t3[j])
                   + zb * x4[j] + bo;
        out[(long)(sb + j) * NDIM + o] = acc[mi][ni][j] + corr;
      }
    }
  }
}

// ---------------- fallback (ws too small): reg-staged fused GEMM --------------
__global__ __launch_bounds__(256) void gemm_fallback(
    const float* __restrict__ x, const float* __restrict__ W,
    const float* __restrict__ A, const float* __restrict__ bias,
    const float* __restrict__ zcw, const float* __restrict__ zcb,
    const float* __restrict__ t, const float* __restrict__ xs,
    float* __restrict__ out) {
  __shared__ __align__(16) unsigned short Asf[2][BM * BK];
  __shared__ __align__(16) unsigned short Wsf[2][BN * BK];
  const int bid = blockIdx.x;
  const int bn = bid & 63, bm = bid >> 6;
  const int tid = threadIdx.x, lane = tid & 63, wid = tid >> 6;
  const int wm = wid >> 1, wn = wid & 1;
  const int srow = tid >> 2, sc0 = (tid & 3) * 16;
  const float* xg = x + (long)(bm * BM + srow) * KDIM + sc0;
  const float* wg = W + (long)(bn * BN + srow) * KDIM + sc0;
  const int off0 = (srow * BK + sc0) ^ ((srow & 7) << 3);
  const int off1 = (srow * BK + sc0 + 8) ^ ((srow & 7) << 3);
  const int fr = lane & 15, fk = (lane >> 4) * 8;
  f32x4 acc[2][2] = {};
  f32x4 xv0, xv1, xv2, xv3, wv0, wv1, wv2, wv3;
  xv0 = *(const f32x4*)(xg);      xv1 = *(const f32x4*)(xg + 4);
  xv2 = *(const f32x4*)(xg + 8);  xv3 = *(const f32x4*)(xg + 12);
  wv0 = *(const f32x4*)(wg);      wv1 = *(const f32x4*)(wg + 4);
  wv2 = *(const f32x4*)(wg + 8);  wv3 = *(const f32x4*)(wg + 12);
  *(bf16x8*)&Asf[0][off0] = pack8(xv0, xv1);
  *(bf16x8*)&Asf[0][off1] = pack8(xv2, xv3);
  *(bf16x8*)&Wsf[0][off0] = pack8(wv0, wv1);
  *(bf16x8*)&Wsf[0][off1] = pack8(wv2, wv3);
  __syncthreads();
  for (int kt = 0; kt < NT; ++kt) {
    const int cur = kt & 1;
    if (kt + 1 < NT) {
      const int off = (kt + 1) * BK;
      xv0 = *(const f32x4*)(xg + off);      xv1 = *(const f32x4*)(xg + off + 4);
      xv2 = *(const f32x4*)(xg + off + 8);  xv3 = *(const f32x4*)(xg + off + 12);
      wv0 = *(const f32x4*)(wg + off);      wv1 = *(const f32x4*)(wg + off + 4);
      wv2 = *(const f32x4*)(wg + off + 8);  wv3 = *(const f32x4*)(wg + off + 12);
    }
    #pragma unroll
    for (int ks = 0; ks < 2; ++ks) {
      const int kk = ks * 32 + fk;
      const int ra0 = wm * 32 + fr, ra1 = ra0 + 16;
      const int rb0 = wn * 32 + fr, rb1 = rb0 + 16;
      bf16x8 a0 = *(const bf16x8*)&Asf[cur][(ra0 * BK + kk) ^ ((ra0 & 7) << 3)];
      bf16x8 a1 = *(const bf16x8*)&Asf[cur][(ra1 * BK + kk) ^ ((ra1 & 7) << 3)];
      bf16x8 b0 = *(const bf16x8*)&Wsf[cur][(rb0 * BK + kk) ^ ((rb0 & 7) << 3)];
      bf16x8 b1 = *(const bf16x8*)&Wsf[cur][(rb1 * BK + kk) ^ ((rb1 & 7) << 3)];
      acc[0][0] = __builtin_amdgcn_mfma_f32_16x16x32_bf16(a0, b0, acc[0][0], 0, 0, 0);
      acc[0][1] = __builtin_amdgcn_mfma_f32_16x16x32_bf16(a0, b1, acc[0][1], 0, 0, 0);
      acc[1][0] = __builtin_amdgcn_mfma_f32_16x16x32_bf16(a1, b0, acc[1][0], 0, 0, 0);
      acc[1][1] = __builtin_amdgcn_mfma_f32_16x16x32_bf16(a1, b1, acc[1][1], 0, 0, 0);
    }
    if (kt + 1 < NT) {
      const int nxt = cur ^ 1;
      *(bf16x8*)&Asf[nxt][off0] = pack8(xv0, xv1);
      *(bf16x8*)&Asf[nxt][off1] = pack8(xv2, xv3);
      *(bf16x8*)&Wsf[nxt][off0] = pack8(wv0, wv1);
      *(bf16x8*)&Wsf[nxt][off1] = pack8(wv2, wv3);
    }
    __syncthreads();
  }
  const float zw8 = zcw[0] * 8.0f;
  const float zb = zcb[0];
  const int s0 = bm * BM + wm * 32;
  const int o0 = bn * BN + wn * 32;
  #pragma unroll
  for (int mi = 0; mi < 2; ++mi) {
    const int sb = s0 + mi * 16 + ((lane >> 4) * 4);
    f32x4 t0 = *(const f32x4*)&t[0 * MDIM + sb];
    f32x4 t1 = *(const f32x4*)&t[1 * MDIM + sb];
    f32x4 t2 = *(const f32x4*)&t[2 * MDIM + sb];
    f32x4 t3 = *(const f32x4*)&t[3 * MDIM + sb];
    f32x4 x4 = *(const f32x4*)&xs[sb];
    #pragma unroll
    for (int ni = 0; ni < 2; ++ni) {
      const int o = o0 + ni * 16 + fr;
      f32x4 a4 = *(const f32x4*)&A[o * 4];
      const float bo = bias[o];
      #pragma unroll
      for (int j = 0; j < 4; ++j) {
        float corr = zw8 * (a4[0] * t0[j] + a4[1] * t1[j] + a4[2] * t2[j] + a4[3] * t3[j])
                   + zb * x4[j] + bo;
        out[(long)(sb + j) * NDIM + o] = acc[mi][ni][j] + corr;
      }
    }
  }
}

extern "C" void kernel_launch(void* const* d_in, const int* in_sizes, int n_in,
                              void* d_out, int out_size, void* d_ws, size_t ws_size,
                              hipStream_t stream) {
  const float* x    = (const float*)d_in[0];
  const float* W    = (const float*)d_in[1];
  const float* A    = (const float*)d_in[2];
  const float* B    = (const float*)d_in[3];
  const float* zcw  = (const float*)d_in[4];
  const float* zcb  = (const float*)d_in[5];
  const float* bias = (const float*)d_in[6];
  float* out = (float*)d_out;

  float* t  = (float*)d_ws;                       // [4][512]
  float* xs = t + 4 * MDIM;                       // [512]
  unsigned short* xbf = (unsigned short*)(xs + MDIM + 1536);  // 16B-align pad; [512][4096] bf16
  unsigned short* wbf = xbf + (size_t)MDIM * KDIM;            // [4096][4096] bf16

  const size_t need = (size_t)(4 * MDIM + MDIM + 1536) * 4
                    + ((size_t)MDIM * KDIM + (size_t)NDIM * KDIM) * 2;

  if (ws_size >= need) {
    prep_kernel<<<MDIM + 2048, 256, 0, stream>>>(x, W, B, t, xs, xbf, wbf);
    gemm_lds<<<(MDIM / BM) * (NDIM / BN), 256, 0, stream>>>(
        xbf, wbf, A, bias, zcw, zcb, t, xs, out);
  } else {
    prep_kernel<<<MDIM, 256, 0, stream>>>(x, W, B, t, xs, nullptr, nullptr);
    gemm_fallback<<<(MDIM / BM) * (NDIM / BN), 256, 0, stream>>>(
        x, W, A, bias, zcw, zcb, t, xs, out);
  }
}

// Round 5
// 62.803 us; speedup vs baseline: 1.2697x; 1.0031x over previous
//
#include <hip/hip_runtime.h>
#include <hip/hip_bf16.h>

// out[s,o] = sum_k x[s,k]*W[o,k]  (bf16 MFMA, global_load_lds, 64x64 wave tiles)
//          + zc_w*8*sum_r A[o,r]*t[r,s] + zc_b*xsum[s] + bias[o]   (fp32 exact)
// prep: W->bf16 (ws), x->bf16 (ws), t[r,s]=sum_k B[r,k]x[s,k], xsum[s]=sum_k x[s,k]

typedef __attribute__((ext_vector_type(8))) short bf16x8;
typedef __attribute__((ext_vector_type(4))) short bf16x4;
typedef __attribute__((ext_vector_type(4))) float f32x4;

#define MDIM 512
#define NDIM 4096
#define KDIM 4096
#define BM 128
#define BN 128
#define BK 64
#define NT (KDIM / BK)   // 64

#define VMCNT(n) asm volatile("s_waitcnt vmcnt(" #n ")" ::: "memory")

static __device__ inline unsigned short f2bf(float f) {
  return __bfloat16_as_ushort(__float2bfloat16(f));  // v_cvt_pk_bf16_f32
}

static __device__ inline bf16x8 pack8(f32x4 a, f32x4 b) {
  bf16x8 v;
  v[0] = (short)f2bf(a[0]); v[1] = (short)f2bf(a[1]);
  v[2] = (short)f2bf(a[2]); v[3] = (short)f2bf(a[3]);
  v[4] = (short)f2bf(b[0]); v[5] = (short)f2bf(b[1]);
  v[6] = (short)f2bf(b[2]); v[7] = (short)f2bf(b[3]);
  return v;
}

static __device__ inline void gll16(const void* g, void* l) {
  __builtin_amdgcn_global_load_lds(
      (const __attribute__((address_space(1))) void*)g,
      (__attribute__((address_space(3))) void*)l, 16, 0, 0);
}

// ---------------- prep: t/xs + x->bf16 (blocks 0..511), W->bf16 (blocks 512+) ----
__global__ __launch_bounds__(256) void prep_kernel(
    const float* __restrict__ x, const float* __restrict__ W,
    const float* __restrict__ B,
    float* __restrict__ t, float* __restrict__ xs,
    unsigned short* __restrict__ xbf, unsigned short* __restrict__ wbf) {
  const int tid = threadIdx.x;
  if (blockIdx.x < MDIM) {
    const int s = blockIdx.x;
    const float* xr = x + (long)s * KDIM;
    float a0 = 0.f, a1 = 0.f, a2 = 0.f, a3 = 0.f, a4 = 0.f;
    for (int k = tid * 4; k < KDIM; k += 1024) {
      f32x4 xv = *(const f32x4*)&xr[k];
      if (xbf) {
        bf16x4 bv;
        bv[0] = (short)f2bf(xv[0]); bv[1] = (short)f2bf(xv[1]);
        bv[2] = (short)f2bf(xv[2]); bv[3] = (short)f2bf(xv[3]);
        *(bf16x4*)&xbf[(long)s * KDIM + k] = bv;
      }
      f32x4 b0 = *(const f32x4*)&B[0 * KDIM + k];
      f32x4 b1 = *(const f32x4*)&B[1 * KDIM + k];
      f32x4 b2 = *(const f32x4*)&B[2 * KDIM + k];
      f32x4 b3 = *(const f32x4*)&B[3 * KDIM + k];
      a0 += xv[0]*b0[0] + xv[1]*b0[1] + xv[2]*b0[2] + xv[3]*b0[3];
      a1 += xv[0]*b1[0] + xv[1]*b1[1] + xv[2]*b1[2] + xv[3]*b1[3];
      a2 += xv[0]*b2[0] + xv[1]*b2[1] + xv[2]*b2[2] + xv[3]*b2[3];
      a3 += xv[0]*b3[0] + xv[1]*b3[1] + xv[2]*b3[2] + xv[3]*b3[3];
      a4 += xv[0] + xv[1] + xv[2] + xv[3];
    }
    #pragma unroll
    for (int off = 32; off; off >>= 1) {
      a0 += __shfl_down(a0, off, 64);
      a1 += __shfl_down(a1, off, 64);
      a2 += __shfl_down(a2, off, 64);
      a3 += __shfl_down(a3, off, 64);
      a4 += __shfl_down(a4, off, 64);
    }
    __shared__ float red[4][5];
    int w = tid >> 6, l = tid & 63;
    if (l == 0) { red[w][0]=a0; red[w][1]=a1; red[w][2]=a2; red[w][3]=a3; red[w][4]=a4; }
    __syncthreads();
    if (tid == 0) {
      t[0 * MDIM + s] = red[0][0] + red[1][0] + red[2][0] + red[3][0];
      t[1 * MDIM + s] = red[0][1] + red[1][1] + red[2][1] + red[3][1];
      t[2 * MDIM + s] = red[0][2] + red[1][2] + red[2][2] + red[3][2];
      t[3 * MDIM + s] = red[0][3] + red[1][3] + red[2][3] + red[3][3];
      xs[s]           = red[0][4] + red[1][4] + red[2][4] + red[3][4];
    }
  } else {
    const long NW = (long)NDIM * KDIM;
    const long stride = (long)(gridDim.x - MDIM) * 256 * 16;
    for (long i = ((long)(blockIdx.x - MDIM) * 256 + tid) * 16; i < NW; i += stride) {
      f32x4 a = *(const f32x4*)&W[i];
      f32x4 b = *(const f32x4*)&W[i + 4];
      f32x4 c = *(const f32x4*)&W[i + 8];
      f32x4 d = *(const f32x4*)&W[i + 12];
      *(bf16x8*)&wbf[i]     = pack8(a, b);
      *(bf16x8*)&wbf[i + 8] = pack8(c, d);
    }
  }
}

// ---------------- main GEMM: 128x128 tile, 4 waves, 64x64 wave tile ------------
// LDS swizzle (both sides, involution): LDS 16B-chunk c of row r holds global
// chunk c ^ (r&7). gll source carries the XOR; frag reads re-apply it.
template<int NSPLIT, bool FUSED>
__global__ __launch_bounds__(256, 2) void gemm_lds2(
    const unsigned short* __restrict__ xb, const unsigned short* __restrict__ wb,
    const float* __restrict__ A, const float* __restrict__ bias,
    const float* __restrict__ zcw, const float* __restrict__ zcb,
    const float* __restrict__ t, const float* __restrict__ xs,
    float* __restrict__ dst) {
  __shared__ __align__(16) unsigned short As[2][BM * BK];
  __shared__ __align__(16) unsigned short Ws[2][BN * BK];

  const int bm = blockIdx.x >> 5;     // 0..3
  const int bn = blockIdx.x & 31;     // 0..31
  const int ks = blockIdx.y;
  const int NTloc = NT / NSPLIT;
  const int kbase = ks * (KDIM / NSPLIT);

  const int tid = threadIdx.x;
  const int lane = tid & 63;
  const int wv = tid >> 6;            // 0..3
  const int wm = wv >> 1;             // 0..1 : rows wm*64..+63
  const int wn = wv & 1;              // 0..1 : cols wn*64..+63

  // staging: per lane 4 chunks per operand. chunk-unit c = i*256 + tid,
  // row = c>>3 (0..127), ch = c&7; source chunk pre-swizzled ch ^ (row&7).
  const int srow8 = lane >> 3;        // row & 7
  const int schk = (lane & 7) ^ srow8;
  const unsigned short* xsrc[4];
  const unsigned short* wsrc[4];
  #pragma unroll
  for (int i = 0; i < 4; ++i) {
    const int row = i * 32 + wv * 8 + srow8;
    xsrc[i] = xb + (long)(bm * BM + row) * KDIM + kbase + schk * 8;
    wsrc[i] = wb + (long)(bn * BN + row) * KDIM + kbase + schk * 8;
  }

  auto STAGE = [&](int kt, int slot) {
    const int koff = kt * BK;
    #pragma unroll
    for (int i = 0; i < 4; ++i) {
      gll16(xsrc[i] + koff, &As[slot][i * 2048 + wv * 512]);
      gll16(wsrc[i] + koff, &Ws[slot][i * 2048 + wv * 512]);
    }
  };

  // fragment read map
  const int fr = lane & 15;
  const int q = lane >> 4;            // 0..3
  const int frs = fr & 7;

  f32x4 acc[4][4] = {};

  auto COMPUTE = [&](int slot) {
    #pragma unroll
    for (int kseg = 0; kseg < 2; ++kseg) {
      const int c = ((kseg * 4 + q) ^ frs) * 8;
      bf16x8 af[4], bf[4];
      #pragma unroll
      for (int mi = 0; mi < 4; ++mi)
        af[mi] = *(const bf16x8*)&As[slot][(wm * 64 + mi * 16 + fr) * BK + c];
      #pragma unroll
      for (int ni = 0; ni < 4; ++ni)
        bf[ni] = *(const bf16x8*)&Ws[slot][(wn * 64 + ni * 16 + fr) * BK + c];
      __builtin_amdgcn_s_setprio(1);
      #pragma unroll
      for (int mi = 0; mi < 4; ++mi)
        #pragma unroll
        for (int ni = 0; ni < 4; ++ni)
          acc[mi][ni] = __builtin_amdgcn_mfma_f32_16x16x32_bf16(
              af[mi], bf[ni], acc[mi][ni], 0, 0, 0);
      __builtin_amdgcn_s_setprio(0);
    }
  };

  STAGE(0, 0);
  for (int kt = 0; kt < NTloc; ++kt) {
    if (kt + 1 < NTloc) {
      STAGE(kt + 1, (kt + 1) & 1);   // slot freed by trailing barrier of kt-1
      VMCNT(8);                      // drain tile kt's 8 gll, leave kt+1 in flight
    } else {
      VMCNT(0);
    }
    __builtin_amdgcn_s_barrier();    // all waves' tile-kt data in LDS
    __builtin_amdgcn_sched_barrier(0);
    COMPUTE(kt & 1);
    __builtin_amdgcn_s_barrier();    // all waves done reading slot kt
  }

  const int s0 = bm * BM + wm * 64;
  const int o0 = bn * BN + wn * 64;
  if (FUSED) {
    const float zw8 = zcw[0] * 8.0f;
    const float zb = zcb[0];
    #pragma unroll
    for (int mi = 0; mi < 4; ++mi) {
      const int sb = s0 + mi * 16 + q * 4;
      f32x4 t0 = *(const f32x4*)&t[0 * MDIM + sb];
      f32x4 t1 = *(const f32x4*)&t[1 * MDIM + sb];
      f32x4 t2 = *(const f32x4*)&t[2 * MDIM + sb];
      f32x4 t3 = *(const f32x4*)&t[3 * MDIM + sb];
      f32x4 x4 = *(const f32x4*)&xs[sb];
      #pragma unroll
      for (int ni = 0; ni < 4; ++ni) {
        const int o = o0 + ni * 16 + fr;
        f32x4 a4 = *(const f32x4*)&A[o * 4];
        const float bo = bias[o];
        #pragma unroll
        for (int j = 0; j < 4; ++j) {
          float corr = zw8 * (a4[0] * t0[j] + a4[1] * t1[j] + a4[2] * t2[j] + a4[3] * t3[j])
                     + zb * x4[j] + bo;
          dst[(long)(sb + j) * NDIM + o] = acc[mi][ni][j] + corr;
        }
      }
    }
  } else {
    float* p = dst + (size_t)ks * MDIM * NDIM;
    #pragma unroll
    for (int mi = 0; mi < 4; ++mi) {
      const int sb = s0 + mi * 16 + q * 4;
      #pragma unroll
      for (int ni = 0; ni < 4; ++ni) {
        const int o = o0 + ni * 16 + fr;
        #pragma unroll
        for (int j = 0; j < 4; ++j)
          p[(long)(sb + j) * NDIM + o] = acc[mi][ni][j];
      }
    }
  }
}

// ---------------- split-K reduce + epilogue ----------------
__global__ __launch_bounds__(256) void reduce_kernel(
    const float* __restrict__ p,
    const float* __restrict__ A, const float* __restrict__ bias,
    const float* __restrict__ zcw, const float* __restrict__ zcb,
    const float* __restrict__ t, const float* __restrict__ xs,
    float* __restrict__ out) {
  const long base = ((long)blockIdx.x * 256 + threadIdx.x) * 4;
  const int s = (int)(base / NDIM);
  const int o = (int)(base % NDIM);
  f32x4 v0 = *(const f32x4*)&p[base];
  f32x4 v1 = *(const f32x4*)&p[(long)MDIM * NDIM + base];
  const float zw8 = zcw[0] * 8.0f;
  const float zb = zcb[0];
  const float t0 = t[0 * MDIM + s], t1 = t[1 * MDIM + s];
  const float t2 = t[2 * MDIM + s], t3 = t[3 * MDIM + s];
  const float xv = xs[s];
  f32x4 bo = *(const f32x4*)&bias[o];
  f32x4 r;
  #pragma unroll
  for (int j = 0; j < 4; ++j) {
    f32x4 a4 = *(const f32x4*)&A[(o + j) * 4];
    r[j] = v0[j] + v1[j]
         + zw8 * (a4[0] * t0 + a4[1] * t1 + a4[2] * t2 + a4[3] * t3)
         + zb * xv + bo[j];
  }
  *(f32x4*)&out[base] = r;
}

// ---------------- fallback (ws too small): reg-staged fused GEMM --------------
__global__ __launch_bounds__(256) void gemm_fallback(
    const float* __restrict__ x, const float* __restrict__ W,
    const float* __restrict__ A, const float* __restrict__ bias,
    const float* __restrict__ zcw, const float* __restrict__ zcb,
    const float* __restrict__ t, const float* __restrict__ xs,
    float* __restrict__ out) {
  __shared__ __align__(16) unsigned short Asf[2][64 * 64];
  __shared__ __align__(16) unsigned short Wsf[2][64 * 64];
  const int bid = blockIdx.x;
  const int bn = bid & 63, bm = bid >> 6;
  const int tid = threadIdx.x, lane = tid & 63, wid = tid >> 6;
  const int wm = wid >> 1, wn = wid & 1;
  const int srow = tid >> 2, sc0 = (tid & 3) * 16;
  const float* xg = x + (long)(bm * 64 + srow) * KDIM + sc0;
  const float* wg = W + (long)(bn * 64 + srow) * KDIM + sc0;
  const int off0 = (srow * 64 + sc0) ^ ((srow & 7) << 3);
  const int off1 = (srow * 64 + sc0 + 8) ^ ((srow & 7) << 3);
  const int fr = lane & 15, fk = (lane >> 4) * 8;
  f32x4 acc[2][2] = {};
  f32x4 xv0, xv1, xv2, xv3, wv0, wv1, wv2, wv3;
  xv0 = *(const f32x4*)(xg);      xv1 = *(const f32x4*)(xg + 4);
  xv2 = *(const f32x4*)(xg + 8);  xv3 = *(const f32x4*)(xg + 12);
  wv0 = *(const f32x4*)(wg);      wv1 = *(const f32x4*)(wg + 4);
  wv2 = *(const f32x4*)(wg + 8);  wv3 = *(const f32x4*)(wg + 12);
  *(bf16x8*)&Asf[0][off0] = pack8(xv0, xv1);
  *(bf16x8*)&Asf[0][off1] = pack8(xv2, xv3);
  *(bf16x8*)&Wsf[0][off0] = pack8(wv0, wv1);
  *(bf16x8*)&Wsf[0][off1] = pack8(wv2, wv3);
  __syncthreads();
  for (int kt = 0; kt < NT; ++kt) {
    const int cur = kt & 1;
    if (kt + 1 < NT) {
      const int off = (kt + 1) * 64;
      xv0 = *(const f32x4*)(xg + off);      xv1 = *(const f32x4*)(xg + off + 4);
      xv2 = *(const f32x4*)(xg + off + 8);  xv3 = *(const f32x4*)(xg + off + 12);
      wv0 = *(const f32x4*)(wg + off);      wv1 = *(const f32x4*)(wg + off + 4);
      wv2 = *(const f32x4*)(wg + off + 8);  wv3 = *(const f32x4*)(wg + off + 12);
    }
    #pragma unroll
    for (int kss = 0; kss < 2; ++kss) {
      const int kk = kss * 32 + fk;
      const int ra0 = wm * 32 + fr, ra1 = ra0 + 16;
      const int rb0 = wn * 32 + fr, rb1 = rb0 + 16;
      bf16x8 a0 = *(const bf16x8*)&Asf[cur][(ra0 * 64 + kk) ^ ((ra0 & 7) << 3)];
      bf16x8 a1 = *(const bf16x8*)&Asf[cur][(ra1 * 64 + kk) ^ ((ra1 & 7) << 3)];
      bf16x8 b0 = *(const bf16x8*)&Wsf[cur][(rb0 * 64 + kk) ^ ((rb0 & 7) << 3)];
      bf16x8 b1 = *(const bf16x8*)&Wsf[cur][(rb1 * 64 + kk) ^ ((rb1 & 7) << 3)];
      acc[0][0] = __builtin_amdgcn_mfma_f32_16x16x32_bf16(a0, b0, acc[0][0], 0, 0, 0);
      acc[0][1] = __builtin_amdgcn_mfma_f32_16x16x32_bf16(a0, b1, acc[0][1], 0, 0, 0);
      acc[1][0] = __builtin_amdgcn_mfma_f32_16x16x32_bf16(a1, b0, acc[1][0], 0, 0, 0);
      acc[1][1] = __builtin_amdgcn_mfma_f32_16x16x32_bf16(a1, b1, acc[1][1], 0, 0, 0);
    }
    if (kt + 1 < NT) {
      const int nxt = cur ^ 1;
      *(bf16x8*)&Asf[nxt][off0] = pack8(xv0, xv1);
      *(bf16x8*)&Asf[nxt][off1] = pack8(xv2, xv3);
      *(bf16x8*)&Wsf[nxt][off0] = pack8(wv0, wv1);
      *(bf16x8*)&Wsf[nxt][off1] = pack8(wv2, wv3);
    }
    __syncthreads();
  }
  const float zw8 = zcw[0] * 8.0f;
  const float zb = zcb[0];
  const int s0 = bm * 64 + wm * 32;
  const int o0 = bn * 64 + wn * 32;
  #pragma unroll
  for (int mi = 0; mi < 2; ++mi) {
    const int sb = s0 + mi * 16 + ((lane >> 4) * 4);
    f32x4 t0 = *(const f32x4*)&t[0 * MDIM + sb];
    f32x4 t1 = *(const f32x4*)&t[1 * MDIM + sb];
    f32x4 t2 = *(const f32x4*)&t[2 * MDIM + sb];
    f32x4 t3 = *(const f32x4*)&t[3 * MDIM + sb];
    f32x4 x4 = *(const f32x4*)&xs[sb];
    #pragma unroll
    for (int ni = 0; ni < 2; ++ni) {
      const int o = o0 + ni * 16 + fr;
      f32x4 a4 = *(const f32x4*)&A[o * 4];
      const float bo = bias[o];
      #pragma unroll
      for (int j = 0; j < 4; ++j) {
        float corr = zw8 * (a4[0] * t0[j] + a4[1] * t1[j] + a4[2] * t2[j] + a4[3] * t3[j])
                   + zb * x4[j] + bo;
        out[(long)(sb + j) * NDIM + o] = acc[mi][ni][j] + corr;
      }
    }
  }
}

extern "C" void kernel_launch(void* const* d_in, const int* in_sizes, int n_in,
                              void* d_out, int out_size, void* d_ws, size_t ws_size,
                              hipStream_t stream) {
  const float* x    = (const float*)d_in[0];
  const float* W    = (const float*)d_in[1];
  const float* A    = (const float*)d_in[2];
  const float* B    = (const float*)d_in[3];
  const float* zcw  = (const float*)d_in[4];
  const float* zcb  = (const float*)d_in[5];
  const float* bias = (const float*)d_in[6];
  float* out = (float*)d_out;

  float* t  = (float*)d_ws;                       // [4][512]
  float* xs = t + 4 * MDIM;                       // [512]
  unsigned short* xbf = (unsigned short*)(xs + MDIM + 1536);  // [512][4096] bf16
  unsigned short* wbf = xbf + (size_t)MDIM * KDIM;            // [4096][4096] bf16
  float* pbuf = (float*)(wbf + (size_t)NDIM * KDIM);          // [2][512][4096] f32

  const size_t base_need = (size_t)(4 * MDIM + MDIM + 1536) * 4
                         + ((size_t)MDIM * KDIM + (size_t)NDIM * KDIM) * 2;
  const size_t split_need = base_need + (size_t)2 * MDIM * NDIM * 4;

  if (ws_size >= base_need) {
    prep_kernel<<<MDIM + 2048, 256, 0, stream>>>(x, W, B, t, xs, xbf, wbf);
    if (ws_size >= split_need) {
      gemm_lds2<2, false><<<dim3(4 * 32, 2), 256, 0, stream>>>(
          xbf, wbf, A, bias, zcw, zcb, t, xs, pbuf);
      reduce_kernel<<<(MDIM * NDIM) / (4 * 256), 256, 0, stream>>>(
          pbuf, A, bias, zcw, zcb, t, xs, out);
    } else {
      gemm_lds2<1, true><<<dim3(4 * 32, 1), 256, 0, stream>>>(
          xbf, wbf, A, bias, zcw, zcb, t, xs, out);
    }
  } else {
    prep_kernel<<<MDIM, 256, 0, stream>>>(x, W, B, t, xs, nullptr, nullptr);
    gemm_fallback<<<(MDIM / 64) * (NDIM / 64), 256, 0, stream>>>(
        x, W, A, bias, zcw, zcb, t, xs, out);
  }
}

// Round 6
// 46.463 us; speedup vs baseline: 1.7162x; 1.3517x over previous
//
#include <hip/hip_runtime.h>
#include <hip/hip_bf16.h>

// out[s,o] = sum_k x[s,k]*W[o,k]  (bf16 MFMA; x via global_load_lds, W fp32
//            reg-staged + cvt_pk -> LDS; split-K=4)
//          + zc_w*8*sum_r A[o,r]*t[r,s] + zc_b*xsum[s] + bias[o]   (fp32 exact)
// prep: x->bf16, t[r,s]=sum_k B[r,k]x[s,k], xsum[s]=sum_k x[s,k]

typedef __attribute__((ext_vector_type(8))) short bf16x8;
typedef __attribute__((ext_vector_type(4))) short bf16x4;
typedef __attribute__((ext_vector_type(4))) unsigned short u16x4;
typedef __attribute__((ext_vector_type(4))) float f32x4;

#define MDIM 512
#define NDIM 4096
#define KDIM 4096
#define BM 128
#define BN 128
#define BK 64
#define NT (KDIM / BK)   // 64

#define VMCNT(n) asm volatile("s_waitcnt vmcnt(" #n ")" ::: "memory")
#define LGKM0()  asm volatile("s_waitcnt lgkmcnt(0)" ::: "memory")

static __device__ inline unsigned short f2bf(float f) {
  return __bfloat16_as_ushort(__float2bfloat16(f));  // v_cvt_pk_bf16_f32
}

static __device__ inline void gll16(const void* g, void* l) {
  __builtin_amdgcn_global_load_lds(
      (const __attribute__((address_space(1))) void*)g,
      (__attribute__((address_space(3))) void*)l, 16, 0, 0);
}

// ---------------- prep: t/xs + x->bf16 ----------------
__global__ __launch_bounds__(256) void tk_kernel(
    const float* __restrict__ x, const float* __restrict__ B,
    float* __restrict__ t, float* __restrict__ xs,
    unsigned short* __restrict__ xbf) {
  const int tid = threadIdx.x;
  const int s = blockIdx.x;
  const float* xr = x + (long)s * KDIM;
  float a0 = 0.f, a1 = 0.f, a2 = 0.f, a3 = 0.f, a4 = 0.f;
  for (int k = tid * 4; k < KDIM; k += 1024) {
    f32x4 xv = *(const f32x4*)&xr[k];
    if (xbf) {
      bf16x4 bv;
      bv[0] = (short)f2bf(xv[0]); bv[1] = (short)f2bf(xv[1]);
      bv[2] = (short)f2bf(xv[2]); bv[3] = (short)f2bf(xv[3]);
      *(bf16x4*)&xbf[(long)s * KDIM + k] = bv;
    }
    f32x4 b0 = *(const f32x4*)&B[0 * KDIM + k];
    f32x4 b1 = *(const f32x4*)&B[1 * KDIM + k];
    f32x4 b2 = *(const f32x4*)&B[2 * KDIM + k];
    f32x4 b3 = *(const f32x4*)&B[3 * KDIM + k];
    a0 += xv[0]*b0[0] + xv[1]*b0[1] + xv[2]*b0[2] + xv[3]*b0[3];
    a1 += xv[0]*b1[0] + xv[1]*b1[1] + xv[2]*b1[2] + xv[3]*b1[3];
    a2 += xv[0]*b2[0] + xv[1]*b2[1] + xv[2]*b2[2] + xv[3]*b2[3];
    a3 += xv[0]*b3[0] + xv[1]*b3[1] + xv[2]*b3[2] + xv[3]*b3[3];
    a4 += xv[0] + xv[1] + xv[2] + xv[3];
  }
  #pragma unroll
  for (int off = 32; off; off >>= 1) {
    a0 += __shfl_down(a0, off, 64);
    a1 += __shfl_down(a1, off, 64);
    a2 += __shfl_down(a2, off, 64);
    a3 += __shfl_down(a3, off, 64);
    a4 += __shfl_down(a4, off, 64);
  }
  __shared__ float red[4][5];
  int w = tid >> 6, l = tid & 63;
  if (l == 0) { red[w][0]=a0; red[w][1]=a1; red[w][2]=a2; red[w][3]=a3; red[w][4]=a4; }
  __syncthreads();
  if (tid == 0) {
    t[0 * MDIM + s] = red[0][0] + red[1][0] + red[2][0] + red[3][0];
    t[1 * MDIM + s] = red[0][1] + red[1][1] + red[2][1] + red[3][1];
    t[2 * MDIM + s] = red[0][2] + red[1][2] + red[2][2] + red[3][2];
    t[3 * MDIM + s] = red[0][3] + red[1][3] + red[2][3] + red[3][3];
    xs[s]           = red[0][4] + red[1][4] + red[2][4] + red[3][4];
  }
}

// ---------------- main GEMM: 128x128 tile, 4 waves, 64x64 wave tile ------------
// x: gll16 -> As (bf16). W: fp32 global->reg (issued 2 tiles early), cvt_pk,
// ds_write -> Ws (bf16). LDS swizzle: 16B chunk c of row r holds global chunk
// c ^ (r&7) (both sides). One s_barrier per K-tile; vmcnt never drained to 0
// in steady state.
template<int NSPLIT, bool FUSED>
__global__ __launch_bounds__(256, 2) void gemm_hyb(
    const unsigned short* __restrict__ xb, const float* __restrict__ W,
    const float* __restrict__ A, const float* __restrict__ bias,
    const float* __restrict__ zcw, const float* __restrict__ zcb,
    const float* __restrict__ t, const float* __restrict__ xs,
    float* __restrict__ dst) {
  __shared__ __align__(16) unsigned short As[2][BM * BK];
  __shared__ __align__(16) unsigned short Ws[2][BN * BK];

  const int bm = blockIdx.x >> 5;     // 0..3
  const int bn = blockIdx.x & 31;     // 0..31
  const int ks = blockIdx.y;
  const int NTloc = NT / NSPLIT;
  const int kbase = ks * (KDIM / NSPLIT);

  const int tid = threadIdx.x;
  const int lane = tid & 63;
  const int wv = tid >> 6;            // 0..3
  const int wm = wv >> 1;             // 0..1
  const int wn = wv & 1;              // 0..1

  // ---- x staging (gll16): wave wv covers rows {i*32 + wv*8 + (lane>>3)} ----
  const int srow8 = lane >> 3;
  const int schk = (lane & 7) ^ srow8;   // pre-swizzled source chunk
  const unsigned short* xsrc[4];
  #pragma unroll
  for (int i = 0; i < 4; ++i) {
    const int row = i * 32 + wv * 8 + srow8;
    xsrc[i] = xb + (long)(bm * BM + row) * KDIM + kbase + schk * 8;
  }
  auto XSTAGE = [&](int kt) {
    const int koff = kt * BK;
    const int slot = kt & 1;
    #pragma unroll
    for (int i = 0; i < 4; ++i)
      gll16(xsrc[i] + koff, &As[slot][i * 2048 + wv * 512]);
  };

  // ---- W staging: lane -> rows wv*32 + (lane>>4) + i*4, fp32 cols (lane&15)*4
  const float* wgp = W + (long)(bn * BN + wv * 32 + (lane >> 4)) * KDIM
                       + kbase + (lane & 15) * 4;
  f32x4 wrE[8], wrO[8];
  auto WISSUE = [&](f32x4 (&wr)[8], int kt) {
    #pragma unroll
    for (int i = 0; i < 8; ++i)
      wr[i] = *(const f32x4*)(wgp + (long)i * 4 * KDIM + kt * BK);
  };
  auto WWRITE = [&](const f32x4 (&wr)[8], int slot) {
    #pragma unroll
    for (int i = 0; i < 8; ++i) {
      const int r = wv * 32 + (lane >> 4) + i * 4;
      const int idx = r * 64 + (((((lane & 15) >> 1)) ^ (r & 7)) << 3) + (lane & 1) * 4;
      u16x4 v;
      v[0] = f2bf(wr[i][0]); v[1] = f2bf(wr[i][1]);
      v[2] = f2bf(wr[i][2]); v[3] = f2bf(wr[i][3]);
      *(u16x4*)&Ws[slot][idx] = v;
    }
  };

  // ---- fragment read map ----
  const int fr = lane & 15;
  const int q = lane >> 4;
  const int frs = fr & 7;

  f32x4 acc[4][4] = {};

  auto COMPUTE = [&](int slot) {
    #pragma unroll
    for (int kseg = 0; kseg < 2; ++kseg) {
      const int c = ((kseg * 4 + q) ^ frs) * 8;
      bf16x8 af[4], bf[4];
      #pragma unroll
      for (int mi = 0; mi < 4; ++mi)
        af[mi] = *(const bf16x8*)&As[slot][(wm * 64 + mi * 16 + fr) * BK + c];
      #pragma unroll
      for (int ni = 0; ni < 4; ++ni)
        bf[ni] = *(const bf16x8*)&Ws[slot][(wn * 64 + ni * 16 + fr) * BK + c];
      __builtin_amdgcn_s_setprio(1);
      #pragma unroll
      for (int mi = 0; mi < 4; ++mi)
        #pragma unroll
        for (int ni = 0; ni < 4; ++ni)
          acc[mi][ni] = __builtin_amdgcn_mfma_f32_16x16x32_bf16(
              af[mi], bf[ni], acc[mi][ni], 0, 0, 0);
      __builtin_amdgcn_s_setprio(0);
    }
  };

  // ---- prologue: Wreg(0)->wrE, xgll(0), Wreg(1)->wrO; stage slot 0 ----
  WISSUE(wrE, 0);
  XSTAGE(0);
  __builtin_amdgcn_sched_barrier(0);
  WISSUE(wrO, 1);
  __builtin_amdgcn_sched_barrier(0);
  WWRITE(wrE, 0);          // compiler waits for wrE
  VMCNT(8);                // xgll(0) landed; Wreg(1) still in flight
  LGKM0();
  __builtin_amdgcn_s_barrier();
  __builtin_amdgcn_sched_barrier(0);

  // ---- steady loop: one barrier per K-tile ----
  // body(kt): xgll(kt+1); Wreg(kt+2); COMPUTE(kt); WWRITE(kt+1); vmcnt(8); bar
  #define BODY(KT, WRISS, WRCON)                                   \
    do {                                                           \
      XSTAGE((KT) + 1);                                            \
      __builtin_amdgcn_sched_barrier(0);                           \
      WISSUE(WRISS, (KT) + 2);                                     \
      COMPUTE((KT) & 1);                                           \
      WWRITE(WRCON, ((KT) + 1) & 1);                               \
      VMCNT(8);                                                    \
      LGKM0();                                                     \
      __builtin_amdgcn_s_barrier();                                \
      __builtin_amdgcn_sched_barrier(0);                           \
    } while (0)

  for (int kt = 0; kt < NTloc - 2; kt += 2) {
    BODY(kt, wrE, wrO);       // even: issue into wrE(kt+2), consume wrO(kt+1)
    BODY(kt + 1, wrO, wrE);   // odd
  }
  // epilogue tile NTloc-2 (even): stage last x tile, no W issue
  XSTAGE(NTloc - 1);
  __builtin_amdgcn_sched_barrier(0);
  COMPUTE((NTloc - 2) & 1);
  WWRITE(wrO, (NTloc - 1) & 1);
  VMCNT(0);
  LGKM0();
  __builtin_amdgcn_s_barrier();
  __builtin_amdgcn_sched_barrier(0);
  // epilogue tile NTloc-1
  COMPUTE((NTloc - 1) & 1);
  #undef BODY

  // ---- epilogue ----
  const int s0 = bm * BM + wm * 64;
  const int o0 = bn * BN + wn * 64;
  if (FUSED) {
    const float zw8 = zcw[0] * 8.0f;
    const float zb = zcb[0];
    #pragma unroll
    for (int mi = 0; mi < 4; ++mi) {
      const int sb = s0 + mi * 16 + q * 4;
      f32x4 t0 = *(const f32x4*)&t[0 * MDIM + sb];
      f32x4 t1 = *(const f32x4*)&t[1 * MDIM + sb];
      f32x4 t2 = *(const f32x4*)&t[2 * MDIM + sb];
      f32x4 t3 = *(const f32x4*)&t[3 * MDIM + sb];
      f32x4 x4 = *(const f32x4*)&xs[sb];
      #pragma unroll
      for (int ni = 0; ni < 4; ++ni) {
        const int o = o0 + ni * 16 + fr;
        f32x4 a4 = *(const f32x4*)&A[o * 4];
        const float bo = bias[o];
        #pragma unroll
        for (int j = 0; j < 4; ++j) {
          float corr = zw8 * (a4[0] * t0[j] + a4[1] * t1[j] + a4[2] * t2[j] + a4[3] * t3[j])
                     + zb * x4[j] + bo;
          dst[(long)(sb + j) * NDIM + o] = acc[mi][ni][j] + corr;
        }
      }
    }
  } else {
    float* p = dst + (size_t)ks * MDIM * NDIM;
    #pragma unroll
    for (int mi = 0; mi < 4; ++mi) {
      const int sb = s0 + mi * 16 + q * 4;
      #pragma unroll
      for (int ni = 0; ni < 4; ++ni) {
        const int o = o0 + ni * 16 + fr;
        #pragma unroll
        for (int j = 0; j < 4; ++j)
          p[(long)(sb + j) * NDIM + o] = acc[mi][ni][j];
      }
    }
  }
}

// ---------------- split-K reduce + epilogue ----------------
__global__ __launch_bounds__(256) void reduce_kernel(
    const float* __restrict__ p,
    const float* __restrict__ A, const float* __restrict__ bias,
    const float* __restrict__ zcw, const float* __restrict__ zcb,
    const float* __restrict__ t, const float* __restrict__ xs,
    float* __restrict__ out) {
  const long base = ((long)blockIdx.x * 256 + threadIdx.x) * 4;
  const int s = (int)(base / NDIM);
  const int o = (int)(base % NDIM);
  f32x4 v0 = *(const f32x4*)&p[base];
  f32x4 v1 = *(const f32x4*)&p[(long)MDIM * NDIM + base];
  f32x4 v2 = *(const f32x4*)&p[(long)2 * MDIM * NDIM + base];
  f32x4 v3 = *(const f32x4*)&p[(long)3 * MDIM * NDIM + base];
  const float zw8 = zcw[0] * 8.0f;
  const float zb = zcb[0];
  const float t0 = t[0 * MDIM + s], t1 = t[1 * MDIM + s];
  const float t2 = t[2 * MDIM + s], t3 = t[3 * MDIM + s];
  const float xv = xs[s];
  f32x4 bo = *(const f32x4*)&bias[o];
  f32x4 r;
  #pragma unroll
  for (int j = 0; j < 4; ++j) {
    f32x4 a4 = *(const f32x4*)&A[(o + j) * 4];
    r[j] = (v0[j] + v1[j]) + (v2[j] + v3[j])
         + zw8 * (a4[0] * t0 + a4[1] * t1 + a4[2] * t2 + a4[3] * t3)
         + zb * xv + bo[j];
  }
  *(f32x4*)&out[base] = r;
}

// ---------------- fallback (ws tiny): reg-staged fused GEMM --------------
__global__ __launch_bounds__(256) void gemm_fallback(
    const float* __restrict__ x, const float* __restrict__ W,
    const float* __restrict__ A, const float* __restrict__ bias,
    const float* __restrict__ zcw, const float* __restrict__ zcb,
    const float* __restrict__ t, const float* __restrict__ xs,
    float* __restrict__ out) {
  __shared__ __align__(16) unsigned short Asf[2][64 * 64];
  __shared__ __align__(16) unsigned short Wsf[2][64 * 64];
  const int bid = blockIdx.x;
  const int bn = bid & 63, bm = bid >> 6;
  const int tid = threadIdx.x, lane = tid & 63, wid = tid >> 6;
  const int wm = wid >> 1, wn = wid & 1;
  const int srow = tid >> 2, sc0 = (tid & 3) * 16;
  const float* xg = x + (long)(bm * 64 + srow) * KDIM + sc0;
  const float* wg = W + (long)(bn * 64 + srow) * KDIM + sc0;
  const int off0 = (srow * 64 + sc0) ^ ((srow & 7) << 3);
  const int off1 = (srow * 64 + sc0 + 8) ^ ((srow & 7) << 3);
  const int fr = lane & 15, fk = (lane >> 4) * 8;
  f32x4 acc[2][2] = {};
  f32x4 xv0, xv1, xv2, xv3, wv0, wv1, wv2, wv3;
  auto pk8 = [](f32x4 a, f32x4 b) {
    bf16x8 v;
    v[0] = (short)f2bf(a[0]); v[1] = (short)f2bf(a[1]);
    v[2] = (short)f2bf(a[2]); v[3] = (short)f2bf(a[3]);
    v[4] = (short)f2bf(b[0]); v[5] = (short)f2bf(b[1]);
    v[6] = (short)f2bf(b[2]); v[7] = (short)f2bf(b[3]);
    return v;
  };
  xv0 = *(const f32x4*)(xg);      xv1 = *(const f32x4*)(xg + 4);
  xv2 = *(const f32x4*)(xg + 8);  xv3 = *(const f32x4*)(xg + 12);
  wv0 = *(const f32x4*)(wg);      wv1 = *(const f32x4*)(wg + 4);
  wv2 = *(const f32x4*)(wg + 8);  wv3 = *(const f32x4*)(wg + 12);
  *(bf16x8*)&Asf[0][off0] = pk8(xv0, xv1);
  *(bf16x8*)&Asf[0][off1] = pk8(xv2, xv3);
  *(bf16x8*)&Wsf[0][off0] = pk8(wv0, wv1);
  *(bf16x8*)&Wsf[0][off1] = pk8(wv2, wv3);
  __syncthreads();
  for (int kt = 0; kt < NT; ++kt) {
    const int cur = kt & 1;
    if (kt + 1 < NT) {
      const int off = (kt + 1) * 64;
      xv0 = *(const f32x4*)(xg + off);      xv1 = *(const f32x4*)(xg + off + 4);
      xv2 = *(const f32x4*)(xg + off + 8);  xv3 = *(const f32x4*)(xg + off + 12);
      wv0 = *(const f32x4*)(wg + off);      wv1 = *(const f32x4*)(wg + off + 4);
      wv2 = *(const f32x4*)(wg + off + 8);  wv3 = *(const f32x4*)(wg + off + 12);
    }
    #pragma unroll
    for (int kss = 0; kss < 2; ++kss) {
      const int kk = kss * 32 + fk;
      const int ra0 = wm * 32 + fr, ra1 = ra0 + 16;
      const int rb0 = wn * 32 + fr, rb1 = rb0 + 16;
      bf16x8 a0 = *(const bf16x8*)&Asf[cur][(ra0 * 64 + kk) ^ ((ra0 & 7) << 3)];
      bf16x8 a1 = *(const bf16x8*)&Asf[cur][(ra1 * 64 + kk) ^ ((ra1 & 7) << 3)];
      bf16x8 b0 = *(const bf16x8*)&Wsf[cur][(rb0 * 64 + kk) ^ ((rb0 & 7) << 3)];
      bf16x8 b1 = *(const bf16x8*)&Wsf[cur][(rb1 * 64 + kk) ^ ((rb1 & 7) << 3)];
      acc[0][0] = __builtin_amdgcn_mfma_f32_16x16x32_bf16(a0, b0, acc[0][0], 0, 0, 0);
      acc[0][1] = __builtin_amdgcn_mfma_f32_16x16x32_bf16(a0, b1, acc[0][1], 0, 0, 0);
      acc[1][0] = __builtin_amdgcn_mfma_f32_16x16x32_bf16(a1, b0, acc[1][0], 0, 0, 0);
      acc[1][1] = __builtin_amdgcn_mfma_f32_16x16x32_bf16(a1, b1, acc[1][1], 0, 0, 0);
    }
    if (kt + 1 < NT) {
      const int nxt = cur ^ 1;
      *(bf16x8*)&Asf[nxt][off0] = pk8(xv0, xv1);
      *(bf16x8*)&Asf[nxt][off1] = pk8(xv2, xv3);
      *(bf16x8*)&Wsf[nxt][off0] = pk8(wv0, wv1);
      *(bf16x8*)&Wsf[nxt][off1] = pk8(wv2, wv3);
    }
    __syncthreads();
  }
  const float zw8 = zcw[0] * 8.0f;
  const float zb = zcb[0];
  const int s0 = bm * 64 + wm * 32;
  const int o0 = bn * 64 + wn * 32;
  #pragma unroll
  for (int mi = 0; mi < 2; ++mi) {
    const int sb = s0 + mi * 16 + ((lane >> 4) * 4);
    f32x4 t0 = *(const f32x4*)&t[0 * MDIM + sb];
    f32x4 t1 = *(const f32x4*)&t[1 * MDIM + sb];
    f32x4 t2 = *(const f32x4*)&t[2 * MDIM + sb];
    f32x4 t3 = *(const f32x4*)&t[3 * MDIM + sb];
    f32x4 x4 = *(const f32x4*)&xs[sb];
    #pragma unroll
    for (int ni = 0; ni < 2; ++ni) {
      const int o = o0 + ni * 16 + fr;
      f32x4 a4 = *(const f32x4*)&A[o * 4];
      const float bo = bias[o];
      #pragma unroll
      for (int j = 0; j < 4; ++j) {
        float corr = zw8 * (a4[0] * t0[j] + a4[1] * t1[j] + a4[2] * t2[j] + a4[3] * t3[j])
                   + zb * x4[j] + bo;
        out[(long)(sb + j) * NDIM + o] = acc[mi][ni][j] + corr;
      }
    }
  }
}

extern "C" void kernel_launch(void* const* d_in, const int* in_sizes, int n_in,
                              void* d_out, int out_size, void* d_ws, size_t ws_size,
                              hipStream_t stream) {
  const float* x    = (const float*)d_in[0];
  const float* W    = (const float*)d_in[1];
  const float* A    = (const float*)d_in[2];
  const float* B    = (const float*)d_in[3];
  const float* zcw  = (const float*)d_in[4];
  const float* zcb  = (const float*)d_in[5];
  const float* bias = (const float*)d_in[6];
  float* out = (float*)d_out;

  float* t  = (float*)d_ws;                       // [4][512]
  float* xs = t + 4 * MDIM;                       // [512]
  unsigned short* xbf = (unsigned short*)(t + 4096);          // [512][4096] bf16
  float* pbuf = (float*)(xbf + (size_t)MDIM * KDIM);          // [4][512][4096] f32

  const size_t need_x = 4096u * 4 + (size_t)MDIM * KDIM * 2;
  const size_t need_p = need_x + (size_t)4 * MDIM * NDIM * 4;

  if (ws_size >= need_p) {
    tk_kernel<<<MDIM, 256, 0, stream>>>(x, B, t, xs, xbf);
    gemm_hyb<4, false><<<dim3(4 * 32, 4), 256, 0, stream>>>(
        xbf, W, A, bias, zcw, zcb, t, xs, pbuf);
    reduce_kernel<<<(MDIM * NDIM) / (4 * 256), 256, 0, stream>>>(
        pbuf, A, bias, zcw, zcb, t, xs, out);
  } else if (ws_size >= need_x) {
    tk_kernel<<<MDIM, 256, 0, stream>>>(x, B, t, xs, xbf);
    gemm_hyb<1, true><<<dim3(4 * 32, 1), 256, 0, stream>>>(
        xbf, W, A, bias, zcw, zcb, t, xs, out);
  } else {
    tk_kernel<<<MDIM, 256, 0, stream>>>(x, B, t, xs, nullptr);
    gemm_fallback<<<(MDIM / 64) * (NDIM / 64), 256, 0, stream>>>(
        x, W, A, bias, zcw, zcb, t, xs, out);
  }
}